// Round 1
// 592.357 us; speedup vs baseline: 1.0977x; 1.0977x over previous
//
#include <hip/hip_runtime.h>
#include <hip/hip_bf16.h>
#include <stdint.h>

typedef __hip_bfloat16 bf16;
typedef __attribute__((ext_vector_type(8))) short short8;
typedef __attribute__((ext_vector_type(4))) float f32x4;

// ---------------- helpers ----------------
__device__ __forceinline__ unsigned short f2bf(float f) {
    bf16 h = __float2bfloat16(f);
    union { bf16 h; unsigned short u; } c; c.h = h; return c.u;
}
__device__ __forceinline__ unsigned int pack2(float a, float b) {
    return (unsigned int)f2bf(a) | ((unsigned int)f2bf(b) << 16);
}

__device__ __forceinline__ void gld16(const void* g, void* l) {
    __builtin_amdgcn_global_load_lds(
        (const __attribute__((address_space(1))) void*)g,
        (__attribute__((address_space(3))) void*)l, 16, 0, 0);
}

// ---------------- fp32 -> bf16 conversions ----------------
__global__ __launch_bounds__(256) void cvt_f32_bf16(
    const float* __restrict__ in, unsigned short* __restrict__ out, long n4)
{
    long i = (long)blockIdx.x * 256 + threadIdx.x;
    if (i >= n4) return;
    float4 v = ((const float4*)in)[i];
    ushort4 o;
    o.x = f2bf(v.x); o.y = f2bf(v.y); o.z = f2bf(v.z); o.w = f2bf(v.w);
    ((ushort4*)out)[i] = o;
}

__global__ __launch_bounds__(256) void cvt_w4(
    const float* __restrict__ a, const float* __restrict__ b,
    const float* __restrict__ c, const float* __restrict__ d,
    unsigned short* __restrict__ out)
{
    const float* src = (blockIdx.y == 0) ? a : (blockIdx.y == 1) ? b
                     : (blockIdx.y == 2) ? c : d;
    long i = (long)blockIdx.x * 256 + threadIdx.x;
    float4 v = ((const float4*)src)[i];
    ushort4 o;
    o.x = f2bf(v.x); o.y = f2bf(v.y); o.z = f2bf(v.z); o.w = f2bf(v.w);
    ((ushort4*)(out + (size_t)blockIdx.y * 1048576))[i] = o;
}

// ---------------- GEMM: 256x256 tile, BK=64, depth-2 counted-vmcnt --------
// C(MxN) = A(MxK) @ B(NxK)^T (+bias). 512 threads = 8 waves (2M x 4N).
// LDS 128 KiB: 2 buffers x (A 32KB + B 32KB), bf16.
// T2: col_byte ^= (row&7)<<4 swizzle, applied BOTH at stage (pre-swizzled
// global source, linear LDS dest per global_load_lds constraint) and at
// ds_read. T3+T4: tile t+2 staged while tile t computes; s_waitcnt vmcnt(8)
// waits only tile t+1 (8 oldest loads), t+2's 8 stay in flight across the
// barrier. T5: setprio around MFMA clusters. No __syncthreads anywhere.

__device__ __forceinline__ void store_c(bf16* C, size_t idx, float v) {
    C[idx] = __float2bfloat16(v);
}
__device__ __forceinline__ void store_c(float* C, size_t idx, float v) {
    C[idx] = v;
}

template <typename CT>
__device__ __forceinline__ void gemm_body256(
    const bf16* __restrict__ A, const bf16* __restrict__ B,
    CT* __restrict__ C, const float* __restrict__ bias,
    int M, int N, int K)
{
    __shared__ char smem[131072];

    const int t    = threadIdx.x;
    const int lane = t & 63;
    const int wave = t >> 6;         // 0..7
    const int wm   = wave >> 2;      // 0..1  M half
    const int wn   = wave & 3;       // 0..3  N quarter
    const int l16  = lane & 15;
    const int quad = lane >> 4;

    // T1: XCD-chunked bijective remap (nwg % 8 == 0 for all our shapes),
    // y-fastest so consecutive wg share the B panel.
    const int gy   = M >> 8;
    const int nwg  = (N >> 8) * gy;
    const int orig = blockIdx.x;
    const int wg   = (orig & 7) * (nwg >> 3) + (orig >> 3);
    const int bx   = wg / gy;
    const int by   = wg - bx * gy;

    const int rowBase = by << 8;
    const int colBase = bx << 8;

    // ---- staging addresses: per K-tile, 4 A-chunks + 4 B-chunks / thread.
    // chunk i (0..2047): LDS byte P=i*16 (linear); row=i>>3; cb=(i&7)*16;
    // global col byte = cb ^ ((row&7)<<4)  (inverse of the read swizzle).
    size_t offA[4], offB[4];
    int ldsOff[4];
#pragma unroll
    for (int r = 0; r < 4; ++r) {
        int i   = (r << 9) + t;
        int row = i >> 3;
        int sw  = ((i & 7) << 4) ^ ((row & 7) << 4);
        offA[r] = (size_t)(rowBase + row) * K + (sw >> 1);
        offB[r] = (size_t)(colBase + row) * K + (sw >> 1);
        ldsOff[r] = i << 4;
    }

    auto stage = [&](int bufsel, int k0) {
        char* bA_ = smem + (bufsel << 16);
        char* bB_ = bA_ + 32768;
#pragma unroll
        for (int r = 0; r < 4; ++r) {
            gld16(A + offA[r] + k0, bA_ + ldsOff[r]);
            gld16(B + offB[r] + k0, bB_ + ldsOff[r]);
        }
    };

    f32x4 acc[8][4];
#pragma unroll
    for (int i = 0; i < 8; ++i)
#pragma unroll
        for (int j = 0; j < 4; ++j) acc[i][j] = (f32x4){0.f, 0.f, 0.f, 0.f};

    // fragment read addressing. rows used by this lane all have
    // row&7 == l16&7 (wm*128, wn*64, mt*16 are all ≡0 mod 8) -> constant xor.
    const int xr   = (l16 & 7) << 4;
    const int kq0  = ((quad << 4)) ^ xr;          // k-half 0
    const int kq1  = (64 + (quad << 4)) ^ xr;     // k-half 1
    const int aRowB = ((wm << 7) + l16) << 7;     // (wm*128 + l16) * 128 B
    const int bRowB = ((wn << 6) + l16) << 7;     // (wn*64  + l16) * 128 B

    // ---- prologue: tiles 0 and 1 in flight; wait tile 0 only (vmcnt(8))
    stage(0, 0);
    stage(1, 64);
    asm volatile("s_waitcnt vmcnt(8)" ::: "memory");
    __builtin_amdgcn_s_barrier();

    const int ntiles = K >> 6;       // 16 for K=1024
    int cur = 0;
    for (int tt = 0; tt < ntiles; ++tt) {
        char* sA = smem + (cur << 16);
        char* sB = sA + 32768;

        // k-half 0 fragments + MFMA
        short8 a0[8], b0[4];
#pragma unroll
        for (int mt = 0; mt < 8; ++mt)
            a0[mt] = *(const short8*)(sA + aRowB + mt * 2048 + kq0);
#pragma unroll
        for (int nt2 = 0; nt2 < 4; ++nt2)
            b0[nt2] = *(const short8*)(sB + bRowB + nt2 * 2048 + kq0);

        __builtin_amdgcn_s_setprio(1);
#pragma unroll
        for (int mt = 0; mt < 8; ++mt)
#pragma unroll
            for (int nt2 = 0; nt2 < 4; ++nt2)
                acc[mt][nt2] = __builtin_amdgcn_mfma_f32_16x16x32_bf16(
                    a0[mt], b0[nt2], acc[mt][nt2], 0, 0, 0);
        __builtin_amdgcn_s_setprio(0);

        // k-half 1 fragments (still reading buf[cur])
        short8 a1[8], b1[4];
#pragma unroll
        for (int mt = 0; mt < 8; ++mt)
            a1[mt] = *(const short8*)(sA + aRowB + mt * 2048 + kq1);
#pragma unroll
        for (int nt2 = 0; nt2 < 4; ++nt2)
            b1[nt2] = *(const short8*)(sB + bRowB + nt2 * 2048 + kq1);

        // all waves finished READING buf[cur] -> safe to overwrite it
        asm volatile("s_waitcnt lgkmcnt(0)" ::: "memory");
        __builtin_amdgcn_s_barrier();

        if (tt + 2 < ntiles) stage(cur, (tt + 2) << 6);

        __builtin_amdgcn_s_setprio(1);
#pragma unroll
        for (int mt = 0; mt < 8; ++mt)
#pragma unroll
            for (int nt2 = 0; nt2 < 4; ++nt2)
                acc[mt][nt2] = __builtin_amdgcn_mfma_f32_16x16x32_bf16(
                    a1[mt], b1[nt2], acc[mt][nt2], 0, 0, 0);
        __builtin_amdgcn_s_setprio(0);

        if (tt + 1 < ntiles) {
            if (tt + 2 < ntiles)
                asm volatile("s_waitcnt vmcnt(8)" ::: "memory"); // tile t+1 done
            else
                asm volatile("s_waitcnt vmcnt(0)" ::: "memory"); // last prefetch
            __builtin_amdgcn_s_barrier();
        }
        cur ^= 1;
    }

    // epilogue
#pragma unroll
    for (int nt2 = 0; nt2 < 4; ++nt2) {
        int col = colBase + (wn << 6) + (nt2 << 4) + l16;
        float bv = bias ? bias[col] : 0.f;
#pragma unroll
        for (int mt = 0; mt < 8; ++mt) {
            int row0 = rowBase + (wm << 7) + (mt << 4) + (quad << 2);
#pragma unroll
            for (int r = 0; r < 4; ++r)
                store_c(C, (size_t)(row0 + r) * N + col, acc[mt][nt2][r] + bv);
        }
    }
}

__global__ __launch_bounds__(512, 2) void gemm_qkv(
    const bf16* __restrict__ A, const bf16* __restrict__ B,
    bf16* __restrict__ C, int M, int N, int K)
{
    gemm_body256<bf16>(A, B, C, nullptr, M, N, K);
}

__global__ __launch_bounds__(512, 2) void gemm_proj(
    const bf16* __restrict__ A, const bf16* __restrict__ B,
    float* __restrict__ C, const float* __restrict__ bias,
    int M, int N, int K)
{
    gemm_body256<float>(A, B, C, bias, M, N, K);
}

// ---------------- MFMA attention over heads, one wave per position --------
// (unchanged this round — see QKV-row comment in previous version)
__global__ __launch_bounds__(256) void attn_heads(
    const bf16* __restrict__ QKV, bf16* __restrict__ Y)
{
    __shared__ char smem[4 * 3264];            // per wave: V 2176B + pad + P 1KB
    const int t    = threadIdx.x;
    const int lane = t & 63;
    const int wave = t >> 6;
    const int l16  = lane & 15;
    const int quad = lane >> 4;

    char* Vp = smem + wave * 3264;             // 16 rows x 136 B (padded)
    char* Pp = smem + wave * 3264 + 2240;      // 16 x 32 bf16 = 1 KB

    const long pos = (long)blockIdx.x * 4 + wave;   // 0..32767
    const int  n   = (int)(pos >> 12);
    const int  s   = (int)(pos & 4095);
    const bf16* base = QKV + pos * 3072;

    uint4 v0 = *(const uint4*)(base + 2048 + lane * 8);
    uint4 v1 = *(const uint4*)(base + 2560 + lane * 8);
    short8 qa0 = *(const short8*)(base +        l16 * 64 + quad * 8);
    short8 qa1 = *(const short8*)(base +        l16 * 64 + quad * 8 + 32);
    short8 kb0 = *(const short8*)(base + 1024 + l16 * 64 + quad * 8);
    short8 kb1 = *(const short8*)(base + 1024 + l16 * 64 + quad * 8 + 32);

    {
        int kh0 = lane >> 3, c = lane & 7;
        *(uint4*)(Vp + kh0 * 136 + c * 16) = v0;
        *(uint4*)(Vp + (kh0 + 8) * 136 + c * 16) = v1;
    }

    *(f32x4*)(Pp + lane * 16) = (f32x4){0.f, 0.f, 0.f, 0.f};

    f32x4 sacc = (f32x4){0.f, 0.f, 0.f, 0.f};
    sacc = __builtin_amdgcn_mfma_f32_16x16x32_bf16(qa0, kb0, sacc, 0, 0, 0);
    sacc = __builtin_amdgcn_mfma_f32_16x16x32_bf16(qa1, kb1, sacc, 0, 0, 0);

    float e[4], sm[4];
#pragma unroll
    for (int r = 0; r < 4; r++) { e[r] = __expf(sacc[r] * 0.125f); sm[r] = e[r]; }
#pragma unroll
    for (int m = 1; m <= 8; m <<= 1) {
#pragma unroll
        for (int r = 0; r < 4; r++) sm[r] += __shfl_xor(sm[r], m);
    }
#pragma unroll
    for (int r = 0; r < 4; r++) {
        float p = e[r] * __builtin_amdgcn_rcpf(sm[r]);
        *(unsigned short*)(Pp + (quad * 4 + r) * 64 + l16 * 2) = f2bf(p);
    }

    short8 pfrag = *(const short8*)(Pp + l16 * 64 + quad * 16);

    const char* gbase = Vp + (quad & 1) * (8 * 136)
                           + ((l16 >> 3) * 16) + ((l16 & 7) * 2);
    const size_t yb = ((size_t)n * 4096 + (size_t)(s >> 4)) * 1024
                    + (size_t)(s & 15) * 64;
#pragma unroll
    for (int f = 0; f < 4; f++) {
        short8 vfrag;
#pragma unroll
        for (int j = 0; j < 8; j++)
            vfrag[j] = *(const short*)(gbase + f * 32 + j * 136);
        f32x4 oc = __builtin_amdgcn_mfma_f32_16x16x32_bf16(
            vfrag, pfrag, (f32x4){0.f, 0.f, 0.f, 0.f}, 0, 0, 0);
        uint2 w;
        w.x = pack2(oc[0], oc[1]);
        w.y = pack2(oc[2], oc[3]);
        *(uint2*)(Y + yb + (size_t)l16 * 262144 + 16 * f + quad * 4) = w;
    }
}

// ---------------- launch ----------------
extern "C" void kernel_launch(void* const* d_in, const int* in_sizes, int n_in,
                              void* d_out, int out_size, void* d_ws, size_t ws_size,
                              hipStream_t stream) {
    const float* x  = (const float*)d_in[0];
    const float* Wq = (const float*)d_in[1];
    const float* Wk = (const float*)d_in[2];
    const float* Wv = (const float*)d_in[3];
    const float* Wo = (const float*)d_in[4];
    const float* bo = (const float*)d_in[5];
    float* out = (float*)d_out;

    const int M = 8 * 4096;                  // 32768 positions
    const size_t MN = (size_t)M * 1024;

    // ws layout (bf16): QKV 192MB | Xb/Yb 64MB | Wcat 6MB | Wob 2MB = 264MB
    bf16* Qkv  = (bf16*)d_ws;
    bf16* Xb   = Qkv + (size_t)M * 3072;
    bf16* Yb   = Xb;                         // X dead after QKV GEMM
    bf16* Wcat = Xb + MN;
    bf16* Wob  = Wcat + (size_t)3072 * 1024;

    {
        long n4 = (long)MN / 4;
        cvt_f32_bf16<<<dim3((unsigned)(n4 / 256)), dim3(256), 0, stream>>>(
            x, (unsigned short*)Xb, n4);
        cvt_w4<<<dim3(1024, 4), dim3(256), 0, stream>>>(
            Wq, Wk, Wv, Wo, (unsigned short*)Wcat);
    }

    dim3 block(512);
    // fused QKV GEMM: C(M x 3072) = X @ [Wq;Wk;Wv]^T ; grid 12*128 = 1536
    gemm_qkv<<<dim3((3072 / 256) * (M / 256)), block, 0, stream>>>(
        Xb, Wcat, Qkv, M, 3072, 1024);
    // attention over heads: 4 positions per block -> 8192 blocks
    attn_heads<<<dim3(M / 4), dim3(256), 0, stream>>>(Qkv, Yb);
    // final projection (fp32 out + bias); grid 4*128 = 512
    gemm_proj<<<dim3((1024 / 256) * (M / 256)), block, 0, stream>>>(
        Yb, Wob, out, bo, M, 1024, 1024);
}

// Round 2
// 591.794 us; speedup vs baseline: 1.0988x; 1.0010x over previous
//
#include <hip/hip_runtime.h>
#include <hip/hip_bf16.h>
#include <stdint.h>

typedef __hip_bfloat16 bf16;
typedef __attribute__((ext_vector_type(8))) short short8;
typedef __attribute__((ext_vector_type(4))) float f32x4;

// ---------------- helpers ----------------
__device__ __forceinline__ unsigned short f2bf(float f) {
    bf16 h = __float2bfloat16(f);
    union { bf16 h; unsigned short u; } c; c.h = h; return c.u;
}
__device__ __forceinline__ unsigned int pack2(float a, float b) {
    return (unsigned int)f2bf(a) | ((unsigned int)f2bf(b) << 16);
}

__device__ __forceinline__ void gld16(const void* g, void* l) {
    __builtin_amdgcn_global_load_lds(
        (const __attribute__((address_space(1))) void*)g,
        (__attribute__((address_space(3))) void*)l, 16, 0, 0);
}

// ---------------- fp32 -> bf16 conversions ----------------
__global__ __launch_bounds__(256) void cvt_f32_bf16(
    const float* __restrict__ in, unsigned short* __restrict__ out, long n4)
{
    long i = (long)blockIdx.x * 256 + threadIdx.x;
    if (i >= n4) return;
    float4 v = ((const float4*)in)[i];
    ushort4 o;
    o.x = f2bf(v.x); o.y = f2bf(v.y); o.z = f2bf(v.z); o.w = f2bf(v.w);
    ((ushort4*)out)[i] = o;
}

__global__ __launch_bounds__(256) void cvt_w4(
    const float* __restrict__ a, const float* __restrict__ b,
    const float* __restrict__ c, const float* __restrict__ d,
    unsigned short* __restrict__ out)
{
    const float* src = (blockIdx.y == 0) ? a : (blockIdx.y == 1) ? b
                     : (blockIdx.y == 2) ? c : d;
    long i = (long)blockIdx.x * 256 + threadIdx.x;
    float4 v = ((const float4*)src)[i];
    ushort4 o;
    o.x = f2bf(v.x); o.y = f2bf(v.y); o.z = f2bf(v.z); o.w = f2bf(v.w);
    ((ushort4*)(out + (size_t)blockIdx.y * 1048576))[i] = o;
}

// ---------------- GEMM: 256x256 tile, BK=64, 4-phase interleave -----------
// C(MxN) = A(MxK) @ B(NxK)^T (+bias). 512 threads = 8 waves (2M x 4N).
// LDS 128 KiB: 2 buffers x (A 32KB + B 32KB), bf16.
// T2: col_byte ^= (row&7)<<4 both-sides swizzle (bank conflicts == 0,
//     verified round 1). T4: counted vmcnt(8), never 0 in steady state.
// T3 (new): each K-tile split into 4 phases of 16 MFMA; each phase ISSUES
// the next quadrant's ds_reads before its MFMA cluster (A0/A1/B0/B1
// register double-buffer), so LDS latency hides under MFMA instead of
// bursting at barriers. Next-tile's first reads issue before the last
// cluster, so the boundary phase overlaps too. T5: setprio per cluster.

__device__ __forceinline__ void store_c(bf16* C, size_t idx, float v) {
    C[idx] = __float2bfloat16(v);
}
__device__ __forceinline__ void store_c(float* C, size_t idx, float v) {
    C[idx] = v;
}

template <typename CT>
__device__ __forceinline__ void gemm_body256(
    const bf16* __restrict__ A, const bf16* __restrict__ B,
    CT* __restrict__ C, const float* __restrict__ bias,
    int M, int N, int K)
{
    __shared__ char smem[131072];

    const int t    = threadIdx.x;
    const int lane = t & 63;
    const int wave = t >> 6;         // 0..7
    const int wm   = wave >> 2;      // 0..1  M half
    const int wn   = wave & 3;       // 0..3  N quarter
    const int l16  = lane & 15;
    const int quad = lane >> 4;

    // T1: XCD-chunked bijective remap (nwg % 8 == 0 for our shapes).
    const int gy   = M >> 8;
    const int nwg  = (N >> 8) * gy;
    const int orig = blockIdx.x;
    const int wg   = (orig & 7) * (nwg >> 3) + (orig >> 3);
    const int bx   = wg / gy;
    const int by   = wg - bx * gy;

    const int rowBase = by << 8;
    const int colBase = bx << 8;

    // staging: chunk i = r*512+t; LDS byte i*16 linear; global source
    // pre-swizzled with the inverse of the read swizzle (rule 21).
    int offA[4], offB[4];
#pragma unroll
    for (int r = 0; r < 4; ++r) {
        int i   = (r << 9) + t;
        int row = i >> 3;
        int sw  = ((i & 7) << 4) ^ ((row & 7) << 4);
        offA[r] = (rowBase + row) * K + (sw >> 1);
        offB[r] = (colBase + row) * K + (sw >> 1);
    }
    const int ldsBase = t << 4;

    auto stage = [&](int bufsel, int k0) {
        char* bA_ = smem + (bufsel << 16);
        char* bB_ = bA_ + 32768;
#pragma unroll
        for (int r = 0; r < 4; ++r) {
            gld16(A + offA[r] + k0, bA_ + ldsBase + (r << 13));
            gld16(B + offB[r] + k0, bB_ + ldsBase + (r << 13));
        }
    };

    f32x4 acc[8][4];
#pragma unroll
    for (int i = 0; i < 8; ++i)
#pragma unroll
        for (int j = 0; j < 4; ++j) acc[i][j] = (f32x4){0.f, 0.f, 0.f, 0.f};

    // fragment addressing (rows used by a lane all have row&7 == l16&7)
    const int xr    = (l16 & 7) << 4;
    const int kq0   = ((quad << 4)) ^ xr;          // k-half 0
    const int kq1   = (64 + (quad << 4)) ^ xr;     // k-half 1
    const int aRowB = ((wm << 7) + l16) << 7;
    const int bRowB = ((wn << 6) + l16) << 7;

    auto rdA = [&](short8* dst, char* sA, int mtbase, int kq) {
#pragma unroll
        for (int m = 0; m < 4; ++m)
            dst[m] = *(const short8*)(sA + aRowB + (mtbase + m) * 2048 + kq);
    };
    auto rdB = [&](short8* dst, char* sB, int kq) {
#pragma unroll
        for (int n = 0; n < 4; ++n)
            dst[n] = *(const short8*)(sB + bRowB + n * 2048 + kq);
    };
    auto cluster = [&](const short8* af, const short8* bfr, int mtbase) {
        __builtin_amdgcn_sched_barrier(0);   // pin cluster after its reads
        __builtin_amdgcn_s_setprio(1);
#pragma unroll
        for (int m = 0; m < 4; ++m)
#pragma unroll
            for (int n = 0; n < 4; ++n)
                acc[mtbase + m][n] = __builtin_amdgcn_mfma_f32_16x16x32_bf16(
                    af[m], bfr[n], acc[mtbase + m][n], 0, 0, 0);
        __builtin_amdgcn_s_setprio(0);
    };

    // ---- prologue: tiles 0,1 in flight; wait tile 0 only
    stage(0, 0);
    stage(1, 64);
    asm volatile("s_waitcnt vmcnt(8)" ::: "memory");
    __builtin_amdgcn_s_barrier();

    short8 A0[4], A1[4], B0[4], B1[4];
    rdA(A0, smem, 0, kq0);
    rdB(B0, smem + 32768, kq0);

    const int ntiles = K >> 6;       // 16 for K=1024
    int cur = 0;
    for (int tt = 0; tt < ntiles; ++tt) {
        char* sA = smem + (cur << 16);
        char* sB = sA + 32768;

        // phase 0: issue A-hi(kh0) reads, MFMA lo x kh0
        rdA(A1, sA, 4, kq0);
        cluster(A0, B0, 0);
        // phase 1: issue A-lo(kh1)+B(kh1) reads, MFMA hi x kh0
        rdA(A0, sA, 0, kq1);
        rdB(B1, sB, kq1);
        cluster(A1, B0, 4);
        // phase 2: issue A-hi(kh1) reads, MFMA lo x kh1
        rdA(A1, sA, 4, kq1);
        cluster(A0, B1, 0);

        // tile boundary: drain own LDS reads, swap/stage with counted vmcnt
        asm volatile("s_waitcnt lgkmcnt(0)" ::: "memory");
        __builtin_amdgcn_sched_barrier(0);
        if (tt + 1 < ntiles) {
            __builtin_amdgcn_s_barrier();            // all waves done reading cur
            if (tt + 2 < ntiles) {
                stage(cur, (tt + 2) << 6);           // overwrite freed buffer
                asm volatile("s_waitcnt vmcnt(8)" ::: "memory");  // t+1 arrived
            } else {
                asm volatile("s_waitcnt vmcnt(0)" ::: "memory");  // last prefetch
            }
            __builtin_amdgcn_s_barrier();
            // phase 3 reads: next tile's A-lo(kh0)+B(kh0), overlap last cluster
            char* nA = smem + ((cur ^ 1) << 16);
            rdA(A0, nA, 0, kq0);
            rdB(B0, nA + 32768, kq0);
        }
        // phase 3: MFMA hi x kh1
        cluster(A1, B1, 4);
        cur ^= 1;
    }

    // epilogue
#pragma unroll
    for (int nt2 = 0; nt2 < 4; ++nt2) {
        int col = colBase + (wn << 6) + (nt2 << 4) + l16;
        float bv = bias ? bias[col] : 0.f;
#pragma unroll
        for (int mt = 0; mt < 8; ++mt) {
            int row0 = rowBase + (wm << 7) + (mt << 4) + (quad << 2);
#pragma unroll
            for (int r = 0; r < 4; ++r)
                store_c(C, (size_t)(row0 + r) * N + col, acc[mt][nt2][r] + bv);
        }
    }
}

__global__ __launch_bounds__(512, 2) void gemm_qkv(
    const bf16* __restrict__ A, const bf16* __restrict__ B,
    bf16* __restrict__ C, int M, int N, int K)
{
    gemm_body256<bf16>(A, B, C, nullptr, M, N, K);
}

__global__ __launch_bounds__(512, 2) void gemm_proj(
    const bf16* __restrict__ A, const bf16* __restrict__ B,
    float* __restrict__ C, const float* __restrict__ bias,
    int M, int N, int K)
{
    gemm_body256<float>(A, B, C, bias, M, N, K);
}

// ---------------- MFMA attention over heads, one wave per position --------
// UNCHANGED this round (kept bit-identical so next round's rocprof top-5
// surfaces it with counters once the GEMMs drop below it).
__global__ __launch_bounds__(256) void attn_heads(
    const bf16* __restrict__ QKV, bf16* __restrict__ Y)
{
    __shared__ char smem[4 * 3264];            // per wave: V 2176B + pad + P 1KB
    const int t    = threadIdx.x;
    const int lane = t & 63;
    const int wave = t >> 6;
    const int l16  = lane & 15;
    const int quad = lane >> 4;

    char* Vp = smem + wave * 3264;             // 16 rows x 136 B (padded)
    char* Pp = smem + wave * 3264 + 2240;      // 16 x 32 bf16 = 1 KB

    const long pos = (long)blockIdx.x * 4 + wave;   // 0..32767
    const int  n   = (int)(pos >> 12);
    const int  s   = (int)(pos & 4095);
    const bf16* base = QKV + pos * 3072;

    uint4 v0 = *(const uint4*)(base + 2048 + lane * 8);
    uint4 v1 = *(const uint4*)(base + 2560 + lane * 8);
    short8 qa0 = *(const short8*)(base +        l16 * 64 + quad * 8);
    short8 qa1 = *(const short8*)(base +        l16 * 64 + quad * 8 + 32);
    short8 kb0 = *(const short8*)(base + 1024 + l16 * 64 + quad * 8);
    short8 kb1 = *(const short8*)(base + 1024 + l16 * 64 + quad * 8 + 32);

    {
        int kh0 = lane >> 3, c = lane & 7;
        *(uint4*)(Vp + kh0 * 136 + c * 16) = v0;
        *(uint4*)(Vp + (kh0 + 8) * 136 + c * 16) = v1;
    }

    *(f32x4*)(Pp + lane * 16) = (f32x4){0.f, 0.f, 0.f, 0.f};

    f32x4 sacc = (f32x4){0.f, 0.f, 0.f, 0.f};
    sacc = __builtin_amdgcn_mfma_f32_16x16x32_bf16(qa0, kb0, sacc, 0, 0, 0);
    sacc = __builtin_amdgcn_mfma_f32_16x16x32_bf16(qa1, kb1, sacc, 0, 0, 0);

    float e[4], sm[4];
#pragma unroll
    for (int r = 0; r < 4; r++) { e[r] = __expf(sacc[r] * 0.125f); sm[r] = e[r]; }
#pragma unroll
    for (int m = 1; m <= 8; m <<= 1) {
#pragma unroll
        for (int r = 0; r < 4; r++) sm[r] += __shfl_xor(sm[r], m);
    }
#pragma unroll
    for (int r = 0; r < 4; r++) {
        float p = e[r] * __builtin_amdgcn_rcpf(sm[r]);
        *(unsigned short*)(Pp + (quad * 4 + r) * 64 + l16 * 2) = f2bf(p);
    }

    short8 pfrag = *(const short8*)(Pp + l16 * 64 + quad * 16);

    const char* gbase = Vp + (quad & 1) * (8 * 136)
                           + ((l16 >> 3) * 16) + ((l16 & 7) * 2);
    const size_t yb = ((size_t)n * 4096 + (size_t)(s >> 4)) * 1024
                    + (size_t)(s & 15) * 64;
#pragma unroll
    for (int f = 0; f < 4; f++) {
        short8 vfrag;
#pragma unroll
        for (int j = 0; j < 8; j++)
            vfrag[j] = *(const short*)(gbase + f * 32 + j * 136);
        f32x4 oc = __builtin_amdgcn_mfma_f32_16x16x32_bf16(
            vfrag, pfrag, (f32x4){0.f, 0.f, 0.f, 0.f}, 0, 0, 0);
        uint2 w;
        w.x = pack2(oc[0], oc[1]);
        w.y = pack2(oc[2], oc[3]);
        *(uint2*)(Y + yb + (size_t)l16 * 262144 + 16 * f + quad * 4) = w;
    }
}

// ---------------- launch ----------------
extern "C" void kernel_launch(void* const* d_in, const int* in_sizes, int n_in,
                              void* d_out, int out_size, void* d_ws, size_t ws_size,
                              hipStream_t stream) {
    const float* x  = (const float*)d_in[0];
    const float* Wq = (const float*)d_in[1];
    const float* Wk = (const float*)d_in[2];
    const float* Wv = (const float*)d_in[3];
    const float* Wo = (const float*)d_in[4];
    const float* bo = (const float*)d_in[5];
    float* out = (float*)d_out;

    const int M = 8 * 4096;                  // 32768 positions
    const size_t MN = (size_t)M * 1024;

    // ws layout (bf16): QKV 192MB | Xb/Yb 64MB | Wcat 6MB | Wob 2MB = 264MB
    bf16* Qkv  = (bf16*)d_ws;
    bf16* Xb   = Qkv + (size_t)M * 3072;
    bf16* Yb   = Xb;                         // X dead after QKV GEMM
    bf16* Wcat = Xb + MN;
    bf16* Wob  = Wcat + (size_t)3072 * 1024;

    {
        long n4 = (long)MN / 4;
        cvt_f32_bf16<<<dim3((unsigned)(n4 / 256)), dim3(256), 0, stream>>>(
            x, (unsigned short*)Xb, n4);
        cvt_w4<<<dim3(1024, 4), dim3(256), 0, stream>>>(
            Wq, Wk, Wv, Wo, (unsigned short*)Wcat);
    }

    dim3 block(512);
    // fused QKV GEMM: C(M x 3072) = X @ [Wq;Wk;Wv]^T ; grid 12*128 = 1536
    gemm_qkv<<<dim3((3072 / 256) * (M / 256)), block, 0, stream>>>(
        Xb, Wcat, Qkv, M, 3072, 1024);
    // attention over heads: 4 positions per block -> 8192 blocks
    attn_heads<<<dim3(M / 4), dim3(256), 0, stream>>>(Qkv, Yb);
    // final projection (fp32 out + bias); grid 4*128 = 512
    gemm_proj<<<dim3((1024 / 256) * (M / 256)), block, 0, stream>>>(
        Yb, Wob, out, bo, M, 1024, 1024);
}